// Round 2
// baseline (217.952 us; speedup 1.0000x reference)
//
#include <hip/hip_runtime.h>
#include <math.h>

// B=16, C=512, HW=1024.  Chain (per batch):
//   X  (C x HW)  = n1 @ W_c^T
//   E  (HW x HW) = X^T @ n2
//   A  = row-softmax(E)
//   out(C x HW)  = n2 @ A
//
// Round 9: fix round-8's gemm3 regression + LDS bank conflicts.
//  - gemm3 now uses the depth-2 register pipeline (like gemm1/2); the
//    softmax exp is applied at ds_write time to a B-set loaded TWO K-steps
//    earlier, so the exp sits parallel to MFMA instead of behind a vmcnt
//    wait. Sc is stored in log2 units -> per element: 1 fma + v_exp_f32.
//  - LDS tile row stride 64B -> 80B (16B aligned). Fragment reads now
//    spread 16 consecutive rows over all 8 bank-groups (20r mod 32) ->
//    <=2-way aliasing (free) instead of the measured 3.1M conflicts.
//    Buffers: A0/A1 @ 0/10240, B0/B1 @ 20480/30720 (40960 B = 4 blocks/CU).
//  - stats_partial: f16x8 (16B) loads, 8 o per thread, 32-row partials.
//
// Workspace (96 MiB, lifetime-aliased):
//   [0,16M):   n2t  f16 (prep -> gemm2)
//   [16,32M):  Xt   f16 (gemm1 -> gemm2)
//   [32,34M):  Wf   f16 (prep -> gemm1; overlaid by Et)
//   [32,64M):  Et   f16 (gemm2 -> stats -> gemm3)
//   [64,80M):  n1f  f16 (prep -> gemm1); Pm/Ps/Sc overlay afterwards
//   [80,96M):  n2f  f16 (prep -> gemm3)

typedef _Float16 f16;
typedef _Float16 f16x8 __attribute__((ext_vector_type(8)));
typedef _Float16 f16x4 __attribute__((ext_vector_type(4)));
typedef float f32x4 __attribute__((ext_vector_type(4)));

#define L2E 1.442695040888963f

// Barrier with LDS-drain only (no vmcnt drain): prefetch survives it.
#define WG_BARRIER() asm volatile("s_waitcnt lgkmcnt(0)\ns_barrier" ::: "memory")

// ---------------------------------------------------------------------------
// Fused pre-pass (unchanged). blockIdx.x:
//   [0,4096):    n1 -> n1f     [4096,4608): Wc -> Wf
//   [4608,6656): n2 -> n2f (natural) + n2t (transposed)
__global__ __launch_bounds__(256) void prep(const float* __restrict__ n1,
                                            const float* __restrict__ Wc,
                                            const float* __restrict__ n2,
                                            f16* __restrict__ n1f, f16* __restrict__ Wf,
                                            f16* __restrict__ n2f, f16* __restrict__ n2t) {
    const int bid = blockIdx.x, tid = threadIdx.x;
    if (bid < 4608) {
        const float* s = (bid < 4096) ? n1 : Wc;
        f16* d = (bid < 4096) ? n1f : Wf;
        const size_t i = ((size_t)(bid < 4096 ? bid : bid - 4096) * 256 + tid) * 8;
        f32x4 a = *(const f32x4*)(s + i);
        f32x4 b = *(const f32x4*)(s + i + 4);
        f16x8 o;
        o[0] = (f16)a[0]; o[1] = (f16)a[1]; o[2] = (f16)a[2]; o[3] = (f16)a[3];
        o[4] = (f16)b[0]; o[5] = (f16)b[1]; o[6] = (f16)b[2]; o[7] = (f16)b[3];
        *(f16x8*)(d + i) = o;
        return;
    }
    const int id = bid - 4608;
    const int b = id >> 7;
    const int ry = (id & 127) >> 4;
    const int cx = id & 15;
    const float* S = n2 + (size_t)b * 512 * 1024;
    f16* Dn = n2f + (size_t)b * 512 * 1024;
    f16* Dt = n2t + (size_t)b * 1024 * 512;
    __shared__ f16 Ts[64 * 72];
    const int r0 = ry * 64, c0 = cx * 64;
    const int rr = tid >> 3, cc8 = (tid & 7) * 8;
#pragma unroll
    for (int h = 0; h < 2; ++h) {
        const int row = r0 + rr + 32 * h;
        const float* s = S + (size_t)row * 1024 + c0 + cc8;
        f32x4 a = *(const f32x4*)s, bq = *(const f32x4*)(s + 4);
        f16x8 o;
        o[0] = (f16)a[0]; o[1] = (f16)a[1]; o[2] = (f16)a[2]; o[3] = (f16)a[3];
        o[4] = (f16)bq[0]; o[5] = (f16)bq[1]; o[6] = (f16)bq[2]; o[7] = (f16)bq[3];
        *(f16x8*)&Ts[(rr + 32 * h) * 72 + cc8] = o;
        *(f16x8*)(Dn + (size_t)row * 1024 + c0 + cc8) = o;
    }
    __syncthreads();
    const int j = tid >> 2, k16 = (tid & 3) * 16;
    f16* d = Dt + (size_t)(c0 + j) * 512 + r0 + k16;
    f16x8 o0, o1;
#pragma unroll
    for (int i = 0; i < 8; ++i) {
        o0[i] = Ts[(k16 + i) * 72 + j];
        o1[i] = Ts[(k16 + 8 + i) * 72 + j];
    }
    *(f16x8*)d = o0;
    *(f16x8*)(d + 8) = o1;
}

// ---------------------------------------------------------------------------
// Column-softmax stats over Et[h][o]. Partials over 32-row sub-chunks.
// Block = (b, chunk64); tid<128 -> rows [0,32), tid>=128 -> rows [32,64).
// Thread owns 8 consecutive o (f16x8 loads).
__global__ __launch_bounds__(256) void stats_partial(const f16* __restrict__ Et,
                                                     float* __restrict__ Pm,
                                                     float* __restrict__ Ps) {
    const int b = blockIdx.x & 15, chunk = blockIdx.x >> 4;
    const int half = threadIdx.x >> 7;
    const int t = threadIdx.x & 127;
    const f16* p = Et + (size_t)b * 1024 * 1024 +
                   ((size_t)chunk * 64 + half * 32) * 1024 + t * 8;
    float m[8], s[8];
#pragma unroll
    for (int c = 0; c < 8; ++c) { m[c] = -3.0e38f; s[c] = 0.f; }
#pragma unroll 4
    for (int j = 0; j < 32; ++j) {
        f16x8 v8 = *(const f16x8*)(p + (size_t)j * 1024);
#pragma unroll
        for (int c = 0; c < 8; ++c) {
            float v = (float)v8[c];
            float nm = fmaxf(m[c], v);
            s[c] = s[c] * __expf(m[c] - nm) + __expf(v - nm);
            m[c] = nm;
        }
    }
    const int idx32 = b * 32 + chunk * 2 + half;
    f32x4 mo0, mo1, so0, so1;
#pragma unroll
    for (int c = 0; c < 4; ++c) { mo0[c] = m[c]; mo1[c] = m[c + 4];
                                  so0[c] = s[c]; so1[c] = s[c + 4]; }
    float* pmo = Pm + (size_t)idx32 * 1024 + t * 8;
    float* pso = Ps + (size_t)idx32 * 1024 + t * 8;
    *(f32x4*)pmo = mo0; *(f32x4*)(pmo + 4) = mo1;
    *(f32x4*)pso = so0; *(f32x4*)(pso + 4) = so1;
}

// stats_combine: per (b,o) fold 32 partials -> Sc[b][o] = (m + log(sum))*log2e.
__global__ __launch_bounds__(256) void stats_combine(const float* __restrict__ Pm,
                                                     const float* __restrict__ Ps,
                                                     float* __restrict__ Sc) {
    const int g = blockIdx.x * 256 + threadIdx.x;  // 16 * 1024
    const int b = g >> 10, o = g & 1023;
    const float* pm = Pm + (size_t)b * 32 * 1024 + o;
    const float* ps = Ps + (size_t)b * 32 * 1024 + o;
    float M = -3.0e38f;
#pragma unroll
    for (int c = 0; c < 32; ++c) M = fmaxf(M, pm[c * 1024]);
    float S = 0.f;
#pragma unroll
    for (int c = 0; c < 32; ++c) S += ps[c * 1024] * __expf(pm[c * 1024] - M);
    Sc[g] = (M + __logf(S)) * L2E;
}

// ---------------------------------------------------------------------------
// Double-buffered K-loop core, 2-deep global->reg prefetch.
//   LDS: A tiles @ 0/10240, B tiles @ 20480/30720. Row stride 80 B
//   (128 rows x 32 f16 data + 16 B pad) -> fragment reads spread rows
//   across all 8 bank-groups (20r mod 32): <=2-way aliasing.
//   Thread stage slot: 16 B at sOff = srow*80 + scolb.
#define GEMM_CORE_D2(NS)                                                                \
    f16x8 pa0 = *(const f16x8*)gAp, pb0 = *(const f16x8*)gBp;                           \
    *(f16x8*)wA0 = pa0; *(f16x8*)wB0 = pb0;                                             \
    f16x8 pa1 = *(const f16x8*)(gAp + 64), pb1 = *(const f16x8*)(gBp + 64);             \
    pa0 = *(const f16x8*)(gAp + 128); pb0 = *(const f16x8*)(gBp + 128);                 \
    WG_BARRIER();                                                                       \
    f32x4 acc[4][2] = {};                                                               \
_Pragma("unroll")                                                                       \
    for (int kb = 0; kb < (NS); ++kb) {                                                 \
        const char* Ac = SM + (kb & 1) * 10240;                                         \
        const char* Bc = SM + 20480 + (kb & 1) * 10240;                                 \
        f16x8 fa[4], fb[2];                                                             \
_Pragma("unroll")                                                                       \
        for (int u = 0; u < 4; ++u)                                                     \
            fa[u] = *(const f16x8*)(Ac + (wm + u * 16 + col) * 80 + quad * 16);         \
_Pragma("unroll")                                                                       \
        for (int v = 0; v < 2; ++v)                                                     \
            fb[v] = *(const f16x8*)(Bc + (wn + v * 16 + col) * 80 + quad * 16);         \
_Pragma("unroll")                                                                       \
        for (int u = 0; u < 4; ++u)                                                     \
_Pragma("unroll")                                                                       \
            for (int v = 0; v < 2; ++v)                                                 \
                acc[u][v] = __builtin_amdgcn_mfma_f32_16x16x32_f16(fa[u], fb[v],        \
                                                                   acc[u][v], 0, 0, 0);\
        if (kb + 1 < (NS)) {                                                            \
            char* dA = SM + ((kb + 1) & 1) * 10240 + sOff;                              \
            char* dB = SM + 20480 + ((kb + 1) & 1) * 10240 + sOff;                      \
            if ((kb & 1) == 0) {                                                        \
                *(f16x8*)dA = pa1; *(f16x8*)dB = pb1;                                   \
                if (kb + 3 < (NS)) {                                                    \
                    pa1 = *(const f16x8*)(gAp + (size_t)(kb + 3) * 64);                 \
                    pb1 = *(const f16x8*)(gBp + (size_t)(kb + 3) * 64);                 \
                }                                                                       \
            } else {                                                                    \
                *(f16x8*)dA = pa0; *(f16x8*)dB = pb0;                                   \
                if (kb + 3 < (NS)) {                                                    \
                    pa0 = *(const f16x8*)(gAp + (size_t)(kb + 3) * 64);                 \
                    pb0 = *(const f16x8*)(gBp + (size_t)(kb + 3) * 64);                 \
                }                                                                       \
            }                                                                           \
            WG_BARRIER();                                                               \
        }                                                                               \
    }

// ---------------------------------------------------------------------------
// GEMM1: Xt[b][o][c] = (n1f[b] @ Wf^T)^T.  M=512, N=1024, K=1024.
__global__ __launch_bounds__(512) void gemm1_nt_xt(const f16* __restrict__ A,
                                                   const f16* __restrict__ Bw,
                                                   f16* __restrict__ Xt) {
    const int M = 512, K = 1024;
    const int id = blockIdx.x;
    const int xcd = id & 7, loc = id >> 3;
    const int b = xcd * 2 + (loc >> 5);
    const int m0 = ((loc >> 3) & 3) * 128;
    const int n0 = (loc & 7) * 128;
    A += (size_t)b * M * K;
    Xt += (size_t)b * 1024 * M;
    __shared__ __attribute__((aligned(16))) char SM[40960];
    const int tid = threadIdx.x, lane = tid & 63, wave = tid >> 6;
    const int col = lane & 15, quad = lane >> 4;
    const int wm = (wave & 1) * 64, wn = (wave >> 1) * 32;
    const int srow = wave * 16 + (lane >> 2), scolb = (lane & 3) * 16;
    const int sOff = srow * 80 + scolb;
    const char* gAp = (const char*)A + (size_t)(m0 + srow) * K * 2 + scolb;
    const char* gBp = (const char*)Bw + (size_t)(n0 + srow) * K * 2 + scolb;
    char* wA0 = SM + sOff;
    char* wB0 = SM + 20480 + sOff;

    GEMM_CORE_D2(32)

    // Transposed epilogue via LDS: Tt[n][m] (pad 136), then coalesced Xt rows.
    WG_BARRIER();  // all frag reads of SM done before overwrite
    f16* Tt = (f16*)SM;
#pragma unroll
    for (int u = 0; u < 4; ++u)
#pragma unroll
        for (int v = 0; v < 2; ++v) {
            f16x4 p;
#pragma unroll
            for (int r = 0; r < 4; ++r) p[r] = (f16)acc[u][v][r];
            *(f16x4*)&Tt[(wn + v * 16 + col) * 136 + wm + u * 16 + quad * 4] = p;
        }
    WG_BARRIER();
    const int j = tid >> 2, seg = (tid & 3) * 32;
    f16* dst = Xt + (size_t)(n0 + j) * M + m0 + seg;
#pragma unroll
    for (int c8 = 0; c8 < 32; c8 += 8)
        *(f16x8*)(dst + c8) = *(const f16x8*)&Tt[j * 136 + seg + c8];
}

// ---------------------------------------------------------------------------
// GEMM2: Et[b][h][o] (f16) = (Xt[b] @ n2t[b]^T)^T.  M=N=1024, K=512.
__global__ __launch_bounds__(512) void gemm2_nt_et(const f16* __restrict__ A,
                                                   const f16* __restrict__ B,
                                                   f16* __restrict__ Et) {
    const int K = 512;
    const int id = blockIdx.x;
    const int xcd = id & 7, loc = id >> 3;
    const int b = xcd * 2 + (loc >> 6);
    const int m0 = ((loc >> 3) & 7) * 128;
    const int n0 = (loc & 7) * 128;
    A += (size_t)b * 1024 * K;
    B += (size_t)b * 1024 * K;
    Et += (size_t)b * 1024 * 1024;
    __shared__ __attribute__((aligned(16))) char SM[40960];
    const int tid = threadIdx.x, lane = tid & 63, wave = tid >> 6;
    const int col = lane & 15, quad = lane >> 4;
    const int wm = (wave & 1) * 64, wn = (wave >> 1) * 32;
    const int srow = wave * 16 + (lane >> 2), scolb = (lane & 3) * 16;
    const int sOff = srow * 80 + scolb;
    const char* gAp = (const char*)A + (size_t)(m0 + srow) * K * 2 + scolb;
    const char* gBp = (const char*)B + (size_t)(n0 + srow) * K * 2 + scolb;
    char* wA0 = SM + sOff;
    char* wB0 = SM + 20480 + sOff;

    GEMM_CORE_D2(16)

    // Et[n][m]: transpose in LDS, write coalesced rows of length 128.
    WG_BARRIER();
    f16* Tt = (f16*)SM;
#pragma unroll
    for (int u = 0; u < 4; ++u)
#pragma unroll
        for (int v = 0; v < 2; ++v) {
            f16x4 p;
#pragma unroll
            for (int r = 0; r < 4; ++r) p[r] = (f16)acc[u][v][r];
            *(f16x4*)&Tt[(wn + v * 16 + col) * 136 + wm + u * 16 + quad * 4] = p;
        }
    WG_BARRIER();
    const int j = tid >> 2, seg = (tid & 3) * 32;
    f16* dst = Et + (size_t)(n0 + j) * 1024 + m0 + seg;
#pragma unroll
    for (int c8 = 0; c8 < 32; c8 += 8)
        *(f16x8*)(dst + c8) = *(const f16x8*)&Tt[j * 136 + seg + c8];
}

// ---------------------------------------------------------------------------
// GEMM3: out[b][c][j] (f32) = n2f[b](f16) @ At[b]^T, with At[j][o] =
// exp2(Et[j][o]*log2e - Sc2[b][o]) computed at ds_write time on a B-set
// loaded TWO K-steps earlier (depth-2 pipeline: exp overlaps MFMA, load
// latency has ~2 steps of cover). M=512, N=1024, K=1024.
__global__ __launch_bounds__(512) void gemm3_nt_out(const f16* __restrict__ A,
                                                    const f16* __restrict__ Et,
                                                    const float* __restrict__ Sc,
                                                    float* __restrict__ C) {
    const int K = 1024, NS = 32;
    const int id = blockIdx.x;
    const int xcd = id & 7, loc = id >> 3;
    const int b = xcd * 2 + (loc >> 5);
    const int m0 = ((loc >> 3) & 3) * 128;
    const int n0 = (loc & 7) * 128;
    A += (size_t)b * 512 * K;
    Et += (size_t)b * 1024 * K;
    Sc += (size_t)b * 1024;
    C += (size_t)b * 512 * 1024;
    __shared__ __attribute__((aligned(16))) char SM[40960];
    const int tid = threadIdx.x, lane = tid & 63, wave = tid >> 6;
    const int col = lane & 15, quad = lane >> 4;
    const int wm = (wave & 1) * 64, wn = (wave >> 1) * 32;
    const int srow = wave * 16 + (lane >> 2), scolb = (lane & 3) * 16;
    const int sOff = srow * 80 + scolb;
    const char* gAp = (const char*)A + (size_t)(m0 + srow) * K * 2 + scolb;
    const char* gBp = (const char*)Et + (size_t)(n0 + srow) * K * 2 + scolb;
    const float* gSp = Sc + (scolb >> 1);  // o-base of this thread's 8 staged elems
    char* wA0 = SM + sOff;
    char* wB0 = SM + 20480 + sOff;

    // Prologue: set0 -> LDS buf0 (exp applied; one uncovered stall, once).
    f16x8 pa0 = *(const f16x8*)gAp, pb0 = *(const f16x8*)gBp;
    f32x4 c00 = *(const f32x4*)gSp, c01 = *(const f32x4*)(gSp + 4);
    {
        f16x8 rbs;
#pragma unroll
        for (int i = 0; i < 4; ++i)
            rbs[i] = (f16)exp2f(fmaf((float)pb0[i], L2E, -c00[i]));
#pragma unroll
        for (int i = 0; i < 4; ++i)
            rbs[4 + i] = (f16)exp2f(fmaf((float)pb0[4 + i], L2E, -c01[i]));
        *(f16x8*)wA0 = pa0;
        *(f16x8*)wB0 = rbs;
    }
    // Prefetch sets 1 and 2 into registers.
    f16x8 pa1 = *(const f16x8*)(gAp + 64), pb1 = *(const f16x8*)(gBp + 64);
    f32x4 c10 = *(const f32x4*)(gSp + 32), c11 = *(const f32x4*)(gSp + 36);
    pa0 = *(const f16x8*)(gAp + 128); pb0 = *(const f16x8*)(gBp + 128);
    c00 = *(const f32x4*)(gSp + 64); c01 = *(const f32x4*)(gSp + 68);
    WG_BARRIER();
    f32x4 acc[4][2] = {};
#pragma unroll
    for (int kb = 0; kb < NS; ++kb) {
        const char* Ac = SM + (kb & 1) * 10240;
        const char* Bc = SM + 20480 + (kb & 1) * 10240;
        f16x8 fa[4], fb[2];
#pragma unroll
        for (int u = 0; u < 4; ++u)
            fa[u] = *(const f16x8*)(Ac + (wm + u * 16 + col) * 80 + quad * 16);
#pragma unroll
        for (int v = 0; v < 2; ++v)
            fb[v] = *(const f16x8*)(Bc + (wn + v * 16 + col) * 80 + quad * 16);
#pragma unroll
        for (int u = 0; u < 4; ++u)
#pragma unroll
            for (int v = 0; v < 2; ++v)
                acc[u][v] = __builtin_amdgcn_mfma_f32_16x16x32_f16(fa[u], fb[v],
                                                                   acc[u][v], 0, 0, 0);
        if (kb + 1 < NS) {
            char* dA = SM + ((kb + 1) & 1) * 10240 + sOff;
            char* dB = SM + 20480 + ((kb + 1) & 1) * 10240 + sOff;
            f16x8 rbs;
            if ((kb & 1) == 0) {
#pragma unroll
                for (int i = 0; i < 4; ++i)
                    rbs[i] = (f16)exp2f(fmaf((float)pb1[i], L2E, -c10[i]));
#pragma unroll
                for (int i = 0; i < 4; ++i)
                    rbs[4 + i] = (f16)exp2f(fmaf((float)pb1[4 + i], L2E, -c11[i]));
                *(f16x8*)dA = pa1;
                *(f16x8*)dB = rbs;
                if (kb + 3 < NS) {
                    pa1 = *(const f16x8*)(gAp + (size_t)(kb + 3) * 64);
                    pb1 = *(const f16x8*)(gBp + (size_t)(kb + 3) * 64);
                    c10 = *(const f32x4*)(gSp + (size_t)(kb + 3) * 32);
                    c11 = *(const f32x4*)(gSp + (size_t)(kb + 3) * 32 + 4);
                }
            } else {
#pragma unroll
                for (int i = 0; i < 4; ++i)
                    rbs[i] = (f16)exp2f(fmaf((float)pb0[i], L2E, -c00[i]));
#pragma unroll
                for (int i = 0; i < 4; ++i)
                    rbs[4 + i] = (f16)exp2f(fmaf((float)pb0[4 + i], L2E, -c01[i]));
                *(f16x8*)dA = pa0;
                *(f16x8*)dB = rbs;
                if (kb + 3 < NS) {
                    pa0 = *(const f16x8*)(gAp + (size_t)(kb + 3) * 64);
                    pb0 = *(const f16x8*)(gBp + (size_t)(kb + 3) * 64);
                    c00 = *(const f32x4*)(gSp + (size_t)(kb + 3) * 32);
                    c01 = *(const f32x4*)(gSp + (size_t)(kb + 3) * 32 + 4);
                }
            }
            WG_BARRIER();
        }
    }

#pragma unroll
    for (int u = 0; u < 4; ++u)
#pragma unroll
        for (int v = 0; v < 2; ++v)
#pragma unroll
            for (int r = 0; r < 4; ++r)
                C[(size_t)(m0 + wm + u * 16 + quad * 4 + r) * 1024 + n0 + wn + v * 16 + col] =
                    acc[u][v][r];
}

// ---------------------------------------------------------------------------
extern "C" void kernel_launch(void* const* d_in, const int* in_sizes, int n_in,
                              void* d_out, int out_size, void* d_ws, size_t ws_size,
                              hipStream_t stream) {
    const float* n1 = (const float*)d_in[0];
    const float* n2 = (const float*)d_in[1];
    const float* Wc = (const float*)d_in[2];
    float* out = (float*)d_out;
    char* ws = (char*)d_ws;

    f16* n2t = (f16*)(ws);                   // [0,16M)   prep -> gemm2
    f16* Xt  = (f16*)(ws + (16u << 20));     // [16,32M)  gemm1 -> gemm2
    f16* Wf  = (f16*)(ws + (32u << 20));     // [32,34M)  prep -> gemm1 (dead before Et)
    f16* Et  = (f16*)(ws + (32u << 20));     // [32,64M)  gemm2 -> stats -> gemm3
    f16* n1f = (f16*)(ws + (64u << 20));     // [64,80M)  prep -> gemm1 (dead after)
    f16* n2f = (f16*)(ws + (80u << 20));     // [80,96M)  prep -> gemm3
    float* Pm = (float*)(ws + (64u << 20));            // 2 MiB, over dead n1f
    float* Ps = (float*)(ws + (66u << 20));            // 2 MiB
    float* Sc = (float*)(ws + (68u << 20));            // 64 KiB (log2 units)

    prep<<<6656, dim3(256), 0, stream>>>(n1, Wc, n2, n1f, Wf, n2f, n2t);
    gemm1_nt_xt<<<512, dim3(512), 0, stream>>>(n1f, Wf, Xt);
    gemm2_nt_et<<<1024, dim3(512), 0, stream>>>(Xt, n2t, Et);
    stats_partial<<<256, dim3(256), 0, stream>>>(Et, Pm, Ps);
    stats_combine<<<64, dim3(256), 0, stream>>>(Pm, Ps, Sc);
    gemm3_nt_out<<<512, dim3(512), 0, stream>>>(n2f, Et, Sc, out);
}

// Round 4
// 205.117 us; speedup vs baseline: 1.0626x; 1.0626x over previous
//
#include <hip/hip_runtime.h>
#include <math.h>

// B=16, C=512, HW=1024.  Chain (per batch):
//   X  (C x HW)  = n1 @ W_c^T
//   E  (HW x HW) = X^T @ n2
//   A  = row-softmax(E)
//   out(C x HW)  = n2 @ A
//
// Round 11 (= round 10 resubmit; previous bench died on container infra).
// All GEMMs: BM=256, BN=128, BK=32, 8 waves, 64x64 wave tiles -> 16 MFMA per
// 8 ds_read_b128 (2x the old ratio; old structure was LDS-read-bound).
// True XOR swizzle (slot s of row r lives at s ^ ((r>>1)&3)) applied
// identically on write and read -> both sides at wave64-minimum bank
// aliasing. Depth-2 register prefetch; gemm3 fuses softmax exp at B-staging.
//
// Workspace (96 MiB, lifetime-aliased):
//   [0,16M):   n2t  f16 (prep -> gemm2)
//   [16,32M):  Xt   f16 (gemm1 -> gemm2)
//   [32,34M):  Wf   f16 (prep -> gemm1; overlaid by Et)
//   [32,64M):  Et   f16 (gemm2 -> stats -> gemm3)
//   [64,80M):  n1f  f16 (prep -> gemm1); Pm/Ps/Sc overlay afterwards
//   [80,96M):  n2f  f16 (prep -> gemm3)

typedef _Float16 f16;
typedef _Float16 f16x8 __attribute__((ext_vector_type(8)));
typedef _Float16 f16x4 __attribute__((ext_vector_type(4)));
typedef float f32x4 __attribute__((ext_vector_type(4)));

#define L2E 1.442695040888963f

// Barrier with LDS-drain only (no vmcnt drain): prefetch survives it.
#define WG_BARRIER() asm volatile("s_waitcnt lgkmcnt(0)\ns_barrier" ::: "memory")

// ---------------------------------------------------------------------------
// Fused pre-pass. blockIdx.x:
//   [0,4096):    n1 -> n1f     [4096,4608): Wc -> Wf
//   [4608,6656): n2 -> n2f (natural) + n2t (transposed)
__global__ __launch_bounds__(256) void prep(const float* __restrict__ n1,
                                            const float* __restrict__ Wc,
                                            const float* __restrict__ n2,
                                            f16* __restrict__ n1f, f16* __restrict__ Wf,
                                            f16* __restrict__ n2f, f16* __restrict__ n2t) {
    const int bid = blockIdx.x, tid = threadIdx.x;
    if (bid < 4608) {
        const float* s = (bid < 4096) ? n1 : Wc;
        f16* d = (bid < 4096) ? n1f : Wf;
        const size_t i = ((size_t)(bid < 4096 ? bid : bid - 4096) * 256 + tid) * 8;
        f32x4 a = *(const f32x4*)(s + i);
        f32x4 b = *(const f32x4*)(s + i + 4);
        f16x8 o;
        o[0] = (f16)a[0]; o[1] = (f16)a[1]; o[2] = (f16)a[2]; o[3] = (f16)a[3];
        o[4] = (f16)b[0]; o[5] = (f16)b[1]; o[6] = (f16)b[2]; o[7] = (f16)b[3];
        *(f16x8*)(d + i) = o;
        return;
    }
    const int id = bid - 4608;
    const int b = id >> 7;
    const int ry = (id & 127) >> 4;
    const int cx = id & 15;
    const float* S = n2 + (size_t)b * 512 * 1024;
    f16* Dn = n2f + (size_t)b * 512 * 1024;
    f16* Dt = n2t + (size_t)b * 1024 * 512;
    __shared__ f16 Ts[64 * 72];
    const int r0 = ry * 64, c0 = cx * 64;
    const int rr = tid >> 3, cc8 = (tid & 7) * 8;
#pragma unroll
    for (int h = 0; h < 2; ++h) {
        const int row = r0 + rr + 32 * h;
        const float* s = S + (size_t)row * 1024 + c0 + cc8;
        f32x4 a = *(const f32x4*)s, bq = *(const f32x4*)(s + 4);
        f16x8 o;
        o[0] = (f16)a[0]; o[1] = (f16)a[1]; o[2] = (f16)a[2]; o[3] = (f16)a[3];
        o[4] = (f16)bq[0]; o[5] = (f16)bq[1]; o[6] = (f16)bq[2]; o[7] = (f16)bq[3];
        *(f16x8*)&Ts[(rr + 32 * h) * 72 + cc8] = o;
        *(f16x8*)(Dn + (size_t)row * 1024 + c0 + cc8) = o;
    }
    __syncthreads();
    const int j = tid >> 2, k16 = (tid & 3) * 16;
    f16* d = Dt + (size_t)(c0 + j) * 512 + r0 + k16;
    f16x8 o0, o1;
#pragma unroll
    for (int i = 0; i < 8; ++i) {
        o0[i] = Ts[(k16 + i) * 72 + j];
        o1[i] = Ts[(k16 + 8 + i) * 72 + j];
    }
    *(f16x8*)d = o0;
    *(f16x8*)(d + 8) = o1;
}

// ---------------------------------------------------------------------------
// Column-softmax stats over Et[h][o]. Partials over 32-row sub-chunks.
__global__ __launch_bounds__(256) void stats_partial(const f16* __restrict__ Et,
                                                     float* __restrict__ Pm,
                                                     float* __restrict__ Ps) {
    const int b = blockIdx.x & 15, chunk = blockIdx.x >> 4;
    const int half = threadIdx.x >> 7;
    const int t = threadIdx.x & 127;
    const f16* p = Et + (size_t)b * 1024 * 1024 +
                   ((size_t)chunk * 64 + half * 32) * 1024 + t * 8;
    float m[8], s[8];
#pragma unroll
    for (int c = 0; c < 8; ++c) { m[c] = -3.0e38f; s[c] = 0.f; }
#pragma unroll 4
    for (int j = 0; j < 32; ++j) {
        f16x8 v8 = *(const f16x8*)(p + (size_t)j * 1024);
#pragma unroll
        for (int c = 0; c < 8; ++c) {
            float v = (float)v8[c];
            float nm = fmaxf(m[c], v);
            s[c] = s[c] * __expf(m[c] - nm) + __expf(v - nm);
            m[c] = nm;
        }
    }
    const int idx32 = b * 32 + chunk * 2 + half;
    f32x4 mo0, mo1, so0, so1;
#pragma unroll
    for (int c = 0; c < 4; ++c) { mo0[c] = m[c]; mo1[c] = m[c + 4];
                                  so0[c] = s[c]; so1[c] = s[c + 4]; }
    float* pmo = Pm + (size_t)idx32 * 1024 + t * 8;
    float* pso = Ps + (size_t)idx32 * 1024 + t * 8;
    *(f32x4*)pmo = mo0; *(f32x4*)(pmo + 4) = mo1;
    *(f32x4*)pso = so0; *(f32x4*)(pso + 4) = so1;
}

// stats_combine: per (b,o) fold 32 partials -> Sc[b][o] = (m + log(sum))*log2e.
__global__ __launch_bounds__(256) void stats_combine(const float* __restrict__ Pm,
                                                     const float* __restrict__ Ps,
                                                     float* __restrict__ Sc) {
    const int g = blockIdx.x * 256 + threadIdx.x;  // 16 * 1024
    const int b = g >> 10, o = g & 1023;
    const float* pm = Pm + (size_t)b * 32 * 1024 + o;
    const float* ps = Ps + (size_t)b * 32 * 1024 + o;
    float M = -3.0e38f;
#pragma unroll
    for (int c = 0; c < 32; ++c) M = fmaxf(M, pm[c * 1024]);
    float S = 0.f;
#pragma unroll
    for (int c = 0; c < 32; ++c) S += ps[c * 1024] * __expf(pm[c * 1024] - M);
    Sc[g] = (M + __logf(S)) * L2E;
}

// ---------------------------------------------------------------------------
// exp-scale of a staged B vector: At = exp2(Et*log2e - Sc2)
__device__ __forceinline__ f16x8 expb(f16x8 b, f32x4 cl, f32x4 ch) {
    f16x8 t;
#pragma unroll
    for (int i = 0; i < 4; ++i) t[i] = (f16)exp2f(fmaf((float)b[i], L2E, -cl[i]));
#pragma unroll
    for (int i = 0; i < 4; ++i) t[4 + i] = (f16)exp2f(fmaf((float)b[4 + i], L2E, -ch[i]));
    return t;
}

// ---------------------------------------------------------------------------
// Shared K-loop core. BM=256, BN=128, BK=32, 512 threads, 8 waves (4m x 2n),
// wave tile 64x64: fa[4] x fb[4] -> 16 MFMA per 8 ds_read_b128.
// LDS: A0 @0 (16K), A1 @16384, B0 @32768 (8K), B1 @40960. Row = 64 B.
// Swizzle: 16B slot s of row r lives at slot s ^ ((r>>1)&3); applied on both
// stage-write (sOff) and fragment-read (swz16).
// Depth-2 global->reg prefetch: set n lives in regs of parity n&1; at step kb
// we ds_write set kb+1 and reload those regs with set kb+3.
template <int NS, bool EXPB>
__device__ __forceinline__ void gemm_core(const char* gA0, const char* gA1,
                                          const char* gB, const float* gSp,
                                          char* SM, int sOff, int wm, int wn,
                                          int col, int swz16, f32x4 (&acc)[4][4]) {
    f16x8 a00 = *(const f16x8*)gA0, a01 = *(const f16x8*)gA1;
    f16x8 b0 = *(const f16x8*)gB;
    f32x4 c00, c01, c10, c11;
    if (EXPB) { c00 = *(const f32x4*)gSp; c01 = *(const f32x4*)(gSp + 4); }
    {
        char* dA = SM + sOff;
        *(f16x8*)dA = a00;
        *(f16x8*)(dA + 8192) = a01;
        char* dB = SM + 32768 + sOff;
        *(f16x8*)dB = EXPB ? expb(b0, c00, c01) : b0;
    }
    f16x8 a10 = *(const f16x8*)(gA0 + 64), a11 = *(const f16x8*)(gA1 + 64);
    f16x8 b1 = *(const f16x8*)(gB + 64);
    if (EXPB) { c10 = *(const f32x4*)(gSp + 32); c11 = *(const f32x4*)(gSp + 36); }
    a00 = *(const f16x8*)(gA0 + 128); a01 = *(const f16x8*)(gA1 + 128);
    b0 = *(const f16x8*)(gB + 128);
    if (EXPB) { c00 = *(const f32x4*)(gSp + 64); c01 = *(const f32x4*)(gSp + 68); }
    WG_BARRIER();
#pragma unroll
    for (int kb = 0; kb < NS; ++kb) {
        const char* Ac = SM + (kb & 1) * 16384;
        const char* Bc = SM + 32768 + (kb & 1) * 8192;
        f16x8 fa[4], fb[4];
#pragma unroll
        for (int u = 0; u < 4; ++u)
            fa[u] = *(const f16x8*)(Ac + (wm + u * 16 + col) * 64 + swz16);
#pragma unroll
        for (int v = 0; v < 4; ++v)
            fb[v] = *(const f16x8*)(Bc + (wn + v * 16 + col) * 64 + swz16);
#pragma unroll
        for (int u = 0; u < 4; ++u)
#pragma unroll
            for (int v = 0; v < 4; ++v)
                acc[u][v] = __builtin_amdgcn_mfma_f32_16x16x32_f16(fa[u], fb[v],
                                                                   acc[u][v], 0, 0, 0);
        if (kb + 1 < NS) {
            char* dA = SM + ((kb + 1) & 1) * 16384 + sOff;
            char* dB = SM + 32768 + ((kb + 1) & 1) * 8192 + sOff;
            if ((kb & 1) == 0) {
                *(f16x8*)dA = a10;
                *(f16x8*)(dA + 8192) = a11;
                *(f16x8*)dB = EXPB ? expb(b1, c10, c11) : b1;
                if (kb + 3 < NS) {
                    a10 = *(const f16x8*)(gA0 + (size_t)(kb + 3) * 64);
                    a11 = *(const f16x8*)(gA1 + (size_t)(kb + 3) * 64);
                    b1 = *(const f16x8*)(gB + (size_t)(kb + 3) * 64);
                    if (EXPB) {
                        c10 = *(const f32x4*)(gSp + (size_t)(kb + 3) * 32);
                        c11 = *(const f32x4*)(gSp + (size_t)(kb + 3) * 32 + 4);
                    }
                }
            } else {
                *(f16x8*)dA = a00;
                *(f16x8*)(dA + 8192) = a01;
                *(f16x8*)dB = EXPB ? expb(b0, c00, c01) : b0;
                if (kb + 3 < NS) {
                    a00 = *(const f16x8*)(gA0 + (size_t)(kb + 3) * 64);
                    a01 = *(const f16x8*)(gA1 + (size_t)(kb + 3) * 64);
                    b0 = *(const f16x8*)(gB + (size_t)(kb + 3) * 64);
                    if (EXPB) {
                        c00 = *(const f32x4*)(gSp + (size_t)(kb + 3) * 32);
                        c01 = *(const f32x4*)(gSp + (size_t)(kb + 3) * 32 + 4);
                    }
                }
            }
            WG_BARRIER();
        }
    }
}

// Transposed f16 epilogue: two m-half passes through Tt[128][136].
__device__ __forceinline__ void epilogue_tr(f32x4 (&acc)[4][4], char* SM, f16* dst0,
                                            int dstRow, int m0, int n0, int tid) {
    const int lane = tid & 63, wave = tid >> 6;
    const int col = lane & 15, quad = lane >> 4;
    const int wn = (wave >> 2) * 64;
    const int mh_w = (wave >> 1) & 1;
    const int wm_loc = (wave & 1) * 64;
    const int j = tid >> 2, seg = (tid & 3) * 32;
    WG_BARRIER();  // all frag reads of SM done before overwrite
    f16* Tt = (f16*)SM;
#pragma unroll
    for (int mh = 0; mh < 2; ++mh) {
        if (mh_w == mh) {
#pragma unroll
            for (int u = 0; u < 4; ++u)
#pragma unroll
                for (int v = 0; v < 4; ++v) {
                    f16x4 p;
#pragma unroll
                    for (int r = 0; r < 4; ++r) p[r] = (f16)acc[u][v][r];
                    *(f16x4*)&Tt[(wn + v * 16 + col) * 136 + wm_loc + u * 16 + quad * 4] = p;
                }
        }
        WG_BARRIER();
        f16* dst = dst0 + (size_t)(n0 + j) * dstRow + m0 + mh * 128 + seg;
#pragma unroll
        for (int c8 = 0; c8 < 32; c8 += 8)
            *(f16x8*)(dst + c8) = *(const f16x8*)&Tt[j * 136 + seg + c8];
        if (mh == 0) WG_BARRIER();
    }
}

// ---------------------------------------------------------------------------
// GEMM1: Xt[b][o][c] = (n1f[b] @ Wf^T)^T.  M=512, N=1024, K=1024. 256 blocks.
__global__ __launch_bounds__(512) void gemm1_nt_xt(const f16* __restrict__ A,
                                                   const f16* __restrict__ Bw,
                                                   f16* __restrict__ Xt) {
    const int K = 1024;
    const int id = blockIdx.x;
    const int xcd = id & 7, loc = id >> 3;         // loc 0..31
    const int b = xcd * 2 + (loc >> 4);
    const int m0 = ((loc >> 3) & 1) * 256;
    const int n0 = (loc & 7) * 128;
    A += (size_t)b * 512 * K;
    Xt += (size_t)b * 1024 * 512;
    __shared__ __attribute__((aligned(16))) char SM[49152];
    const int tid = threadIdx.x, lane = tid & 63, wave = tid >> 6;
    const int col = lane & 15, quad = lane >> 4;
    const int wm = (wave & 3) * 64, wn = (wave >> 2) * 64;
    const int srow = tid >> 2, sslot = tid & 3;
    const int sOff = srow * 64 + ((sslot ^ ((srow >> 1) & 3)) * 16);
    const int swz16 = (quad ^ ((col >> 1) & 3)) * 16;
    const char* gA0 = (const char*)A + (size_t)(m0 + srow) * K * 2 + sslot * 16;
    const char* gA1 = gA0 + (size_t)128 * K * 2;
    const char* gB = (const char*)Bw + (size_t)(n0 + srow) * K * 2 + sslot * 16;
    f32x4 acc[4][4] = {};
    gemm_core<32, false>(gA0, gA1, gB, nullptr, SM, sOff, wm, wn, col, swz16, acc);
    epilogue_tr(acc, SM, Xt, 512, m0, n0, tid);
}

// ---------------------------------------------------------------------------
// GEMM2: Et[b][h][o] (f16) = (Xt[b] @ n2t[b]^T)^T.  M=1024, N=1024, K=512.
// 512 blocks.
__global__ __launch_bounds__(512) void gemm2_nt_et(const f16* __restrict__ A,
                                                   const f16* __restrict__ B,
                                                   f16* __restrict__ Et) {
    const int K = 512;
    const int id = blockIdx.x;
    const int xcd = id & 7, loc = id >> 3;         // loc 0..63
    const int b = xcd * 2 + (loc >> 5);
    const int m0 = ((loc >> 3) & 3) * 256;
    const int n0 = (loc & 7) * 128;
    A += (size_t)b * 1024 * K;
    B += (size_t)b * 1024 * K;
    Et += (size_t)b * 1024 * 1024;
    __shared__ __attribute__((aligned(16))) char SM[49152];
    const int tid = threadIdx.x, lane = tid & 63, wave = tid >> 6;
    const int col = lane & 15, quad = lane >> 4;
    const int wm = (wave & 3) * 64, wn = (wave >> 2) * 64;
    const int srow = tid >> 2, sslot = tid & 3;
    const int sOff = srow * 64 + ((sslot ^ ((srow >> 1) & 3)) * 16);
    const int swz16 = (quad ^ ((col >> 1) & 3)) * 16;
    const char* gA0 = (const char*)A + (size_t)(m0 + srow) * K * 2 + sslot * 16;
    const char* gA1 = gA0 + (size_t)128 * K * 2;
    const char* gB = (const char*)B + (size_t)(n0 + srow) * K * 2 + sslot * 16;
    f32x4 acc[4][4] = {};
    gemm_core<16, false>(gA0, gA1, gB, nullptr, SM, sOff, wm, wn, col, swz16, acc);
    epilogue_tr(acc, SM, Et, 1024, m0, n0, tid);
}

// ---------------------------------------------------------------------------
// GEMM3: out[b][c][j] (f32) = n2f[b](f16) @ At[b]^T, At[j][o] =
// exp2(Et[j][o]*log2e - Sc[b][o]) applied at B-staging (depth-2 covered).
// M=512, N=1024, K=1024. 256 blocks.
__global__ __launch_bounds__(512) void gemm3_nt_out(const f16* __restrict__ A,
                                                    const f16* __restrict__ Et,
                                                    const float* __restrict__ Sc,
                                                    float* __restrict__ C) {
    const int K = 1024;
    const int id = blockIdx.x;
    const int xcd = id & 7, loc = id >> 3;         // loc 0..31
    const int b = xcd * 2 + (loc >> 4);
    const int m0 = ((loc >> 3) & 1) * 256;
    const int n0 = (loc & 7) * 128;
    A += (size_t)b * 512 * K;
    Et += (size_t)b * 1024 * K;
    Sc += (size_t)b * 1024;
    C += (size_t)b * 512 * 1024;
    __shared__ __attribute__((aligned(16))) char SM[49152];
    const int tid = threadIdx.x, lane = tid & 63, wave = tid >> 6;
    const int col = lane & 15, quad = lane >> 4;
    const int wm = (wave & 3) * 64, wn = (wave >> 2) * 64;
    const int srow = tid >> 2, sslot = tid & 3;
    const int sOff = srow * 64 + ((sslot ^ ((srow >> 1) & 3)) * 16);
    const int swz16 = (quad ^ ((col >> 1) & 3)) * 16;
    const char* gA0 = (const char*)A + (size_t)(m0 + srow) * K * 2 + sslot * 16;
    const char* gA1 = gA0 + (size_t)128 * K * 2;
    const char* gB = (const char*)Et + (size_t)(n0 + srow) * K * 2 + sslot * 16;
    const float* gSp = Sc + sslot * 8;  // K-base of this thread's 8 staged elems
    f32x4 acc[4][4] = {};
    gemm_core<32, true>(gA0, gA1, gB, gSp, SM, sOff, wm, wn, col, swz16, acc);

#pragma unroll
    for (int u = 0; u < 4; ++u)
#pragma unroll
        for (int v = 0; v < 4; ++v)
#pragma unroll
            for (int r = 0; r < 4; ++r)
                C[(size_t)(m0 + wm + u * 16 + quad * 4 + r) * 1024 + n0 + wn + v * 16 + col] =
                    acc[u][v][r];
}

// ---------------------------------------------------------------------------
extern "C" void kernel_launch(void* const* d_in, const int* in_sizes, int n_in,
                              void* d_out, int out_size, void* d_ws, size_t ws_size,
                              hipStream_t stream) {
    const float* n1 = (const float*)d_in[0];
    const float* n2 = (const float*)d_in[1];
    const float* Wc = (const float*)d_in[2];
    float* out = (float*)d_out;
    char* ws = (char*)d_ws;

    f16* n2t = (f16*)(ws);                   // [0,16M)   prep -> gemm2
    f16* Xt  = (f16*)(ws + (16u << 20));     // [16,32M)  gemm1 -> gemm2
    f16* Wf  = (f16*)(ws + (32u << 20));     // [32,34M)  prep -> gemm1 (dead before Et)
    f16* Et  = (f16*)(ws + (32u << 20));     // [32,64M)  gemm2 -> stats -> gemm3
    f16* n1f = (f16*)(ws + (64u << 20));     // [64,80M)  prep -> gemm1 (dead after)
    f16* n2f = (f16*)(ws + (80u << 20));     // [80,96M)  prep -> gemm3
    float* Pm = (float*)(ws + (64u << 20));            // 2 MiB, over dead n1f
    float* Ps = (float*)(ws + (66u << 20));            // 2 MiB
    float* Sc = (float*)(ws + (68u << 20));            // 64 KiB (log2 units)

    prep<<<6656, dim3(256), 0, stream>>>(n1, Wc, n2, n1f, Wf, n2f, n2t);
    gemm1_nt_xt<<<256, dim3(512), 0, stream>>>(n1f, Wf, Xt);
    gemm2_nt_et<<<512, dim3(512), 0, stream>>>(Xt, n2t, Et);
    stats_partial<<<256, dim3(256), 0, stream>>>(Et, Pm, Ps);
    stats_combine<<<64, dim3(256), 0, stream>>>(Pm, Ps, Sc);
    gemm3_nt_out<<<256, dim3(512), 0, stream>>>(n2f, Et, Sc, out);
}